// Round 1
// baseline (197.549 us; speedup 1.0000x reference)
//
#include <hip/hip_runtime.h>
#include <hip/hip_bf16.h>
#include <math.h>

// Problem constants (from reference)
#define BATCH   2
#define SEQ     512     // N
#define DIN     512
#define DM      256     // d_model

// Fast, overflow-free tanh: e = exp(-2|x|) in (0,1]; t = (1-e)/(1+e); sign-restore.
__device__ __forceinline__ float fast_tanh(float x) {
    float ax = fabsf(x);
    float e  = __expf(-2.0f * ax);
    float t  = __fdividef(1.0f - e, 1.0f + e);
    return copysignf(t, x);
}

// ---------------- Kernel A: h = tanh(x @ Wx + bx), h in workspace ----------------
// grid = (B*N)/ROWS blocks, 256 threads; thread = output column d.
#define ROWS 4
__global__ __launch_bounds__(256) void h_kernel(
    const float* __restrict__ x,    // [B*N, DIN]
    const float* __restrict__ Wx,   // [DIN, DM]
    const float* __restrict__ bx,   // [DM]
    float* __restrict__ h)          // [B*N, DM]
{
    const int row0 = blockIdx.x * ROWS;
    const int tid  = threadIdx.x;   // d in [0,256)

    float acc[ROWS];
    float b = bx[tid];
    #pragma unroll
    for (int r = 0; r < ROWS; r++) acc[r] = b;

    const float* xr = x + (size_t)row0 * DIN;
    for (int k = 0; k < DIN; k++) {
        float wx = Wx[(size_t)k * DM + tid];   // coalesced, L2-resident
        #pragma unroll
        for (int r = 0; r < ROWS; r++)
            acc[r] = fmaf(xr[(size_t)r * DIN + k], wx, acc[r]);  // uniform addr -> s_load
    }
    #pragma unroll
    for (int r = 0; r < ROWS; r++)
        h[(size_t)(row0 + r) * DM + tid] = fast_tanh(acc[r]);
}

// ---------------- Kernel B: scores + softmax + weighted sum ----------------
// grid = B*N blocks (one per (b,i) row), 256 threads.
__global__ __launch_bounds__(256) void attn_kernel(
    const float* __restrict__ pos,   // [B, N, 4]
    const int*   __restrict__ mask,  // [B, N, N]
    const float* __restrict__ Wp,    // [4, DM]
    const float* __restrict__ bp,    // [DM]
    const float* __restrict__ wv,    // [DM]
    const float* __restrict__ h,     // [B, N, DM]
    float* __restrict__ out,         // [B, N, DM]
    float* __restrict__ attn_out)    // [B, N, N]
{
    const int bi  = blockIdx.x;
    const int b   = bi >> 9;         // N = 512
    const int i   = bi & (SEQ - 1);
    const int tid = threadIdx.x;

    __shared__ float4 s_wp[DM];      // {Wp[0][d],Wp[1][d],Wp[2][d],Wp[3][d]}
    __shared__ float2 s_bw[DM];      // {bp[d], w[d]}
    __shared__ float4 s_pos[SEQ];    // pos[b, j, :]
    __shared__ float  s_p[SEQ];      // softmax probs
    __shared__ float  s_red[4];

    // stage weights and the pos tile for this batch
    s_wp[tid] = make_float4(Wp[tid], Wp[DM + tid], Wp[2*DM + tid], Wp[3*DM + tid]);
    s_bw[tid] = make_float2(bp[tid], wv[tid]);
    const float4* posv = (const float4*)(pos + (size_t)b * SEQ * 4);
    s_pos[tid]       = posv[tid];
    s_pos[tid + 256] = posv[tid + 256];
    __syncthreads();

    const float4 pi = s_pos[i];

    // ---- phase 1: raw scores for j = tid and j = tid+256 ----
    float score[2];
    #pragma unroll
    for (int jj = 0; jj < 2; jj++) {
        const int j = tid + jj * 256;
        const float4 pj = s_pos[j];
        const float r0 = pi.x - pj.x, r1 = pi.y - pj.y,
                    r2 = pi.z - pj.z, r3 = pi.w - pj.w;
        float acc = 0.0f;
        #pragma unroll 4
        for (int d = 0; d < DM; d++) {
            const float4 wp = s_wp[d];      // LDS broadcast (uniform)
            const float2 bw = s_bw[d];      // LDS broadcast (uniform)
            float t = fmaf(r0, wp.x, fmaf(r1, wp.y, fmaf(r2, wp.z, fmaf(r3, wp.w, bw.x))));
            acc = fmaf(bw.y, fast_tanh(t), acc);
        }
        score[jj] = acc;
    }

    // ---- phase 2: masked softmax over j ----
    const size_t mbase = (size_t)b * SEQ * SEQ + (size_t)i * SEQ;
    const int m0 = mask[mbase + tid];
    const int m1 = mask[mbase + tid + 256];
    float v0 = m0 ? score[0] : -INFINITY;
    float v1 = m1 ? score[1] : -INFINITY;

    // block max
    float vmax = fmaxf(v0, v1);
    #pragma unroll
    for (int off = 32; off; off >>= 1) vmax = fmaxf(vmax, __shfl_xor(vmax, off, 64));
    if ((tid & 63) == 0) s_red[tid >> 6] = vmax;
    __syncthreads();
    vmax = fmaxf(fmaxf(s_red[0], s_red[1]), fmaxf(s_red[2], s_red[3]));
    __syncthreads();   // protect s_red reuse

    float p0 = m0 ? __expf(v0 - vmax) : 0.0f;
    float p1 = m1 ? __expf(v1 - vmax) : 0.0f;

    // block sum
    float psum = p0 + p1;
    #pragma unroll
    for (int off = 32; off; off >>= 1) psum += __shfl_xor(psum, off, 64);
    if ((tid & 63) == 0) s_red[tid >> 6] = psum;
    __syncthreads();
    psum = (s_red[0] + s_red[1]) + (s_red[2] + s_red[3]);

    const float inv = __fdividef(1.0f, psum);
    p0 *= inv;
    p1 *= inv;

    attn_out[mbase + tid]       = p0;
    attn_out[mbase + tid + 256] = p1;
    s_p[tid]       = p0;
    s_p[tid + 256] = p1;
    __syncthreads();

    // ---- phase 3: out[b,i,d] = sum_j p[j] * h[b,j,d] ----
    const float* hb = h + (size_t)b * SEQ * DM;
    float acc = 0.0f;
    #pragma unroll 4
    for (int j = 0; j < SEQ; j++)
        acc = fmaf(s_p[j], hb[(size_t)j * DM + tid], acc);   // coalesced h reads
    out[(size_t)bi * DM + tid] = acc;
}

extern "C" void kernel_launch(void* const* d_in, const int* in_sizes, int n_in,
                              void* d_out, int out_size, void* d_ws, size_t ws_size,
                              hipStream_t stream) {
    const float* x    = (const float*)d_in[0];
    const float* pos  = (const float*)d_in[1];
    const int*   mask = (const int*)  d_in[2];
    const float* Wx   = (const float*)d_in[3];
    const float* bx   = (const float*)d_in[4];
    const float* Wp   = (const float*)d_in[5];
    const float* bp   = (const float*)d_in[6];
    const float* wv   = (const float*)d_in[7];

    float* out      = (float*)d_out;                          // [B,N,DM]
    float* attn_out = (float*)d_out + (size_t)BATCH*SEQ*DM;   // [B,N,N]
    float* h        = (float*)d_ws;                           // [B,N,DM] scratch

    h_kernel<<<(BATCH*SEQ)/ROWS, 256, 0, stream>>>(x, Wx, bx, h);
    attn_kernel<<<BATCH*SEQ, 256, 0, stream>>>(pos, mask, Wp, bp, wv, h, out, attn_out);
}

// Round 2
// 143.196 us; speedup vs baseline: 1.3796x; 1.3796x over previous
//
#include <hip/hip_runtime.h>
#include <hip/hip_bf16.h>
#include <math.h>

// Problem constants (from reference)
#define BATCH   2
#define SEQ     512     // N
#define DIN     512
#define DM      256     // d_model

#define LOG2E2  2.88539008177792681f   // 2*log2(e)

#if __has_builtin(__builtin_amdgcn_exp2f)
#define EXP2(x) __builtin_amdgcn_exp2f(x)
#else
#define EXP2(x) exp2f(x)
#endif
#if __has_builtin(__builtin_amdgcn_rcpf)
#define RCP(x) __builtin_amdgcn_rcpf(x)
#else
#define RCP(x) (1.0f / (x))
#endif

// tanh(t) where targ = 2*log2(e)*t already applied:
// tanh = 1 - 2/(1 + exp2(targ)). Overflow-correct: targ->+inf => 1, -inf => -1.
__device__ __forceinline__ float tanh_from_scaled(float targ) {
    return fmaf(-2.0f, RCP(1.0f + EXP2(targ)), 1.0f);
}

// ---------------- Kernel A: h = tanh(x @ Wx + bx) ----------------
// grid = (B*N)/2 blocks, 256 threads; thread = output column d, 2 rows/block.
__global__ __launch_bounds__(256) void h_kernel(
    const float* __restrict__ x,    // [B*N, DIN]
    const float* __restrict__ Wx,   // [DIN, DM]
    const float* __restrict__ bx,   // [DM]
    float* __restrict__ h)          // [B*N, DM]
{
    const int row0 = blockIdx.x * 2;
    const int tid  = threadIdx.x;   // d in [0,256)

    float acc0 = bx[tid];
    float acc1 = acc0;

    const float* __restrict__ x0 = x + (size_t)row0 * DIN;
    const float* __restrict__ x1 = x0 + DIN;

    #pragma unroll 8
    for (int k = 0; k < DIN; k++) {
        const float wxv = Wx[(size_t)k * DM + tid];   // coalesced vector load
        acc0 = fmaf(x0[k], wxv, acc0);                // x uniform -> s_load
        acc1 = fmaf(x1[k], wxv, acc1);
    }
    h[(size_t)row0 * DM + tid]       = tanh_from_scaled(LOG2E2 * acc0);
    h[(size_t)(row0 + 1) * DM + tid] = tanh_from_scaled(LOG2E2 * acc1);
}

// ---------------- Kernel B: scores + softmax + weighted sum ----------------
// grid = B*N blocks (one per (b,i) row), 256 threads; each thread owns j=tid, tid+256.
__global__ __launch_bounds__(256) void attn_kernel(
    const float* __restrict__ pos,   // [B, N, 4]
    const int*   __restrict__ mask,  // [B, N, N]
    const float* __restrict__ Wp,    // [4, DM]
    const float* __restrict__ bp,    // [DM]
    const float* __restrict__ wv,    // [DM]
    const float* __restrict__ h,     // [B, N, DM]
    float* __restrict__ out,         // [B, N, DM]
    float* __restrict__ attn_out)    // [B, N, N]
{
    const int bi  = blockIdx.x;
    const int b   = bi >> 9;         // N = 512
    const int i   = bi & (SEQ - 1);
    const int tid = threadIdx.x;

    __shared__ float4 s_pos[SEQ];    // pos[b, j, :] pre-scaled by 2*log2e
    __shared__ float  s_p[SEQ];      // softmax probs
    __shared__ float  s_red[4];

    // stage the pos tile for this batch, pre-scaled so the exp2 arg needs no mul
    const float4* __restrict__ posv = (const float4*)(pos + (size_t)b * SEQ * 4);
    {
        float4 a = posv[tid];
        float4 c = posv[tid + 256];
        s_pos[tid]       = make_float4(a.x*LOG2E2, a.y*LOG2E2, a.z*LOG2E2, a.w*LOG2E2);
        s_pos[tid + 256] = make_float4(c.x*LOG2E2, c.y*LOG2E2, c.z*LOG2E2, c.w*LOG2E2);
    }
    __syncthreads();

    const float4 pi  = s_pos[i];
    const float4 pj0 = s_pos[tid];
    const float4 pj1 = s_pos[tid + 256];

    const float r00 = pi.x - pj0.x, r01 = pi.y - pj0.y, r02 = pi.z - pj0.z, r03 = pi.w - pj0.w;
    const float r10 = pi.x - pj1.x, r11 = pi.y - pj1.y, r12 = pi.z - pj1.z, r13 = pi.w - pj1.w;

    // ---- phase 1: a = sum_d w[d] / (1 + exp2(c*(rel . Wp_d + bp_d))) ----
    // score = Wsum - 2a; softmax is shift-invariant so use -2a directly.
    float a0 = 0.0f, a1 = 0.0f;
    #pragma unroll 4
    for (int d = 0; d < DM; d++) {
        // wave-uniform addresses on const __restrict__ inputs -> scalar loads
        const float wp0 = Wp[d];
        const float wp1 = Wp[DM + d];
        const float wp2 = Wp[2*DM + d];
        const float wp3 = Wp[3*DM + d];
        const float bpc = LOG2E2 * bp[d];   // uniform -> SALU
        const float wd  = wv[d];

        const float t0 = fmaf(r00, wp0, fmaf(r01, wp1, fmaf(r02, wp2, fmaf(r03, wp3, bpc))));
        const float t1 = fmaf(r10, wp0, fmaf(r11, wp1, fmaf(r12, wp2, fmaf(r13, wp3, bpc))));
        a0 = fmaf(wd, RCP(1.0f + EXP2(t0)), a0);
        a1 = fmaf(wd, RCP(1.0f + EXP2(t1)), a1);
    }
    const float score0 = -2.0f * a0;
    const float score1 = -2.0f * a1;

    // ---- phase 2: masked softmax over j ----
    const size_t mbase = (size_t)b * SEQ * SEQ + (size_t)i * SEQ;
    const int m0 = mask[mbase + tid];
    const int m1 = mask[mbase + tid + 256];
    float v0 = m0 ? score0 : -INFINITY;
    float v1 = m1 ? score1 : -INFINITY;

    float vmax = fmaxf(v0, v1);
    #pragma unroll
    for (int off = 32; off; off >>= 1) vmax = fmaxf(vmax, __shfl_xor(vmax, off, 64));
    if ((tid & 63) == 0) s_red[tid >> 6] = vmax;
    __syncthreads();
    vmax = fmaxf(fmaxf(s_red[0], s_red[1]), fmaxf(s_red[2], s_red[3]));
    __syncthreads();   // protect s_red reuse

    float p0 = m0 ? __expf(v0 - vmax) : 0.0f;
    float p1 = m1 ? __expf(v1 - vmax) : 0.0f;

    float psum = p0 + p1;
    #pragma unroll
    for (int off = 32; off; off >>= 1) psum += __shfl_xor(psum, off, 64);
    if ((tid & 63) == 0) s_red[tid >> 6] = psum;
    __syncthreads();
    psum = (s_red[0] + s_red[1]) + (s_red[2] + s_red[3]);

    const float inv = __fdividef(1.0f, psum);
    p0 *= inv;
    p1 *= inv;

    attn_out[mbase + tid]       = p0;
    attn_out[mbase + tid + 256] = p1;
    s_p[tid]       = p0;
    s_p[tid + 256] = p1;
    __syncthreads();

    // ---- phase 3: out[b,i,d] = sum_j p[j] * h[b,j,d] ----
    const float* __restrict__ hb = h + (size_t)b * SEQ * DM;
    const float4* __restrict__ pv = (const float4*)s_p;
    float acc = 0.0f;
    #pragma unroll 4
    for (int j4 = 0; j4 < SEQ/4; j4++) {
        const float4 p = pv[j4];                      // one ds_read_b128 per 4 j
        const float* hj = hb + (size_t)(j4*4) * DM + tid;
        acc = fmaf(p.x, hj[0*DM], acc);
        acc = fmaf(p.y, hj[1*DM], acc);
        acc = fmaf(p.z, hj[2*DM], acc);
        acc = fmaf(p.w, hj[3*DM], acc);
    }
    out[(size_t)bi * DM + tid] = acc;
}

extern "C" void kernel_launch(void* const* d_in, const int* in_sizes, int n_in,
                              void* d_out, int out_size, void* d_ws, size_t ws_size,
                              hipStream_t stream) {
    const float* x    = (const float*)d_in[0];
    const float* pos  = (const float*)d_in[1];
    const int*   mask = (const int*)  d_in[2];
    const float* Wx   = (const float*)d_in[3];
    const float* bx   = (const float*)d_in[4];
    const float* Wp   = (const float*)d_in[5];
    const float* bp   = (const float*)d_in[6];
    const float* wv   = (const float*)d_in[7];

    float* out      = (float*)d_out;                          // [B,N,DM]
    float* attn_out = (float*)d_out + (size_t)BATCH*SEQ*DM;   // [B,N,N]
    float* h        = (float*)d_ws;                           // [B,N,DM] scratch

    h_kernel<<<(BATCH*SEQ)/2, 256, 0, stream>>>(x, Wx, bx, h);
    attn_kernel<<<BATCH*SEQ, 256, 0, stream>>>(pos, mask, Wp, bp, wv, h, out, attn_out);
}

// Round 3
// 142.676 us; speedup vs baseline: 1.3846x; 1.0036x over previous
//
#include <hip/hip_runtime.h>
#include <hip/hip_bf16.h>
#include <math.h>

// Problem constants (from reference)
#define BATCH   2
#define SEQ     512     // N
#define DIN     512
#define DM      256     // d_model

#define LOG2E2  2.88539008177792681f   // 2*log2(e)

#if __has_builtin(__builtin_amdgcn_exp2f)
#define EXP2(x) __builtin_amdgcn_exp2f(x)
#else
#define EXP2(x) exp2f(x)
#endif
#if __has_builtin(__builtin_amdgcn_rcpf)
#define RCP(x) __builtin_amdgcn_rcpf(x)
#else
#define RCP(x) (1.0f / (x))
#endif

// tanh(t) with targ = 2*log2(e)*t: tanh = 1 - 2/(1 + exp2(targ)); overflow-safe.
__device__ __forceinline__ float tanh_from_scaled(float targ) {
    return fmaf(-2.0f, RCP(1.0f + EXP2(targ)), 1.0f);
}

// ---------------- Kernel P: EA/EB factor tables ----------------
// EA[b,i,d] = exp2(c*(pos_i.Wp_d + bp_d)); EB2[b][d][j&255].{x,y} = exp2(-c*pos_j.Wp_d)
// grid = B*N blocks, 256 threads (d = tid).
__global__ __launch_bounds__(256) void pre_kernel(
    const float* __restrict__ pos,   // [B, N, 4]
    const float* __restrict__ Wp,    // [4, DM]
    const float* __restrict__ bp,    // [DM]
    float* __restrict__ EA,          // [B*N, DM]
    float* __restrict__ EB2)         // [B][DM][256] float2 (j, j+256)
{
    const int bi = blockIdx.x;
    const int b  = bi >> 9;
    const int n  = bi & (SEQ - 1);
    const int d  = threadIdx.x;

    const float4 p = ((const float4*)pos)[bi];   // uniform -> s_load
    const float P = fmaf(p.x, Wp[d],
                    fmaf(p.y, Wp[DM + d],
                    fmaf(p.z, Wp[2*DM + d],
                         p.w * Wp[3*DM + d])));

    EA[(size_t)bi * DM + d] = EXP2(LOG2E2 * (P + bp[d]));   // coalesced

    // scattered store (one dword per (d)); small table, L2-resident
    EB2[(((size_t)(b * DM + d)) * 256 + (n & 255)) * 2 + (n >> 8)] = EXP2(-LOG2E2 * P);
}

// ---------------- Kernel A: h = tanh(x @ Wx + bx) ----------------
// grid = (B*N)/4 blocks, 256 threads; wave = row, lane = 4 cols (float4).
__global__ __launch_bounds__(256) void h_kernel(
    const float* __restrict__ x,    // [B*N, DIN]
    const float* __restrict__ Wx,   // [DIN, DM]
    const float* __restrict__ bx,   // [DM]
    float* __restrict__ h)          // [B*N, DM]
{
    __shared__ float4 s_x[4][DIN/4];   // 4 rows x 512 floats = 8 KB

    const int tid = threadIdx.x;
    const int w   = tid >> 6;          // wave id = local row
    const int l   = tid & 63;          // lane -> cols 4l..4l+3
    const int row = blockIdx.x * 4 + w;

    // stage this wave's x row (coalesced float4)
    const float4* __restrict__ xr = (const float4*)(x + (size_t)row * DIN);
    s_x[w][l]      = xr[l];
    s_x[w][l + 64] = xr[l + 64];
    __syncthreads();

    float4 acc = ((const float4*)bx)[l];
    const float* __restrict__ wxp = Wx + 4 * l;

    #pragma unroll 2
    for (int k4 = 0; k4 < DIN/4; k4++) {
        const float4 xv = s_x[w][k4];                     // ds_read_b128 broadcast
        const float4 w0 = *(const float4*)(wxp + (size_t)(4*k4 + 0) * DM);
        const float4 w1 = *(const float4*)(wxp + (size_t)(4*k4 + 1) * DM);
        const float4 w2 = *(const float4*)(wxp + (size_t)(4*k4 + 2) * DM);
        const float4 w3 = *(const float4*)(wxp + (size_t)(4*k4 + 3) * DM);
        acc.x = fmaf(xv.x, w0.x, acc.x); acc.y = fmaf(xv.x, w0.y, acc.y);
        acc.z = fmaf(xv.x, w0.z, acc.z); acc.w = fmaf(xv.x, w0.w, acc.w);
        acc.x = fmaf(xv.y, w1.x, acc.x); acc.y = fmaf(xv.y, w1.y, acc.y);
        acc.z = fmaf(xv.y, w1.z, acc.z); acc.w = fmaf(xv.y, w1.w, acc.w);
        acc.x = fmaf(xv.z, w2.x, acc.x); acc.y = fmaf(xv.z, w2.y, acc.y);
        acc.z = fmaf(xv.z, w2.z, acc.z); acc.w = fmaf(xv.z, w2.w, acc.w);
        acc.x = fmaf(xv.w, w3.x, acc.x); acc.y = fmaf(xv.w, w3.y, acc.y);
        acc.z = fmaf(xv.w, w3.z, acc.z); acc.w = fmaf(xv.w, w3.w, acc.w);
    }

    float4 r;
    r.x = tanh_from_scaled(LOG2E2 * acc.x);
    r.y = tanh_from_scaled(LOG2E2 * acc.y);
    r.z = tanh_from_scaled(LOG2E2 * acc.z);
    r.w = tanh_from_scaled(LOG2E2 * acc.w);
    ((float4*)(h + (size_t)row * DM))[l] = r;
}

// ---------------- Kernel B: scores + softmax + weighted sum ----------------
// grid = B*N/2 blocks (2 i-rows per block), 256 threads; thread owns j=tid, tid+256.
__global__ __launch_bounds__(256) void attn_kernel(
    const int*   __restrict__ mask,  // [B, N, N]
    const float* __restrict__ wv,    // [DM]
    const float* __restrict__ EA,    // [B*N, DM]
    const float* __restrict__ EB2,   // [B][DM][256] float2
    const float* __restrict__ h,     // [B, N, DM]
    float* __restrict__ out,         // [B, N, DM]
    float* __restrict__ attn_out)    // [B, N, N]
{
    const int b   = blockIdx.x >> 8;
    const int ig  = blockIdx.x & 255;
    const int i0  = ig * 2;
    const int tid = threadIdx.x;

    __shared__ float s_p0[SEQ], s_p1[SEQ];
    __shared__ float s_red[2][4];

    const float* __restrict__ EAp0 = EA + (size_t)(b * SEQ + i0) * DM;   // uniform -> s_load
    const float* __restrict__ EAp1 = EAp0 + DM;
    const float2* __restrict__ EBp = (const float2*)EB2 + (size_t)b * DM * 256 + tid;

    // ---- phase 1: a[i][jj] = sum_d w_d / (1 + EA[i,d]*EB[d,j]) ----
    // score = const - 2a (softmax shift-invariant): smaller a => larger score.
    float a00 = 0.f, a01 = 0.f, a10 = 0.f, a11 = 0.f;
    #pragma unroll 4
    for (int d = 0; d < DM; d++) {
        const float2 eb = EBp[(size_t)d * 256];   // coalesced dwordx2
        const float ea0 = EAp0[d];
        const float ea1 = EAp1[d];
        const float wd  = wv[d];
        a00 = fmaf(wd, RCP(fmaf(ea0, eb.x, 1.0f)), a00);
        a01 = fmaf(wd, RCP(fmaf(ea0, eb.y, 1.0f)), a01);
        a10 = fmaf(wd, RCP(fmaf(ea1, eb.x, 1.0f)), a10);
        a11 = fmaf(wd, RCP(fmaf(ea1, eb.y, 1.0f)), a11);
    }

    // ---- phase 2: masked softmax (minimize a; p = exp2(K*(amin-a))) ----
    const size_t mb0 = (size_t)b * SEQ * SEQ + (size_t)i0 * SEQ;
    const size_t mb1 = mb0 + SEQ;
    const int m00 = mask[mb0 + tid], m01 = mask[mb0 + tid + 256];
    const int m10 = mask[mb1 + tid], m11 = mask[mb1 + tid + 256];

    float v0 = fminf(m00 ? a00 : INFINITY, m01 ? a01 : INFINITY);
    float v1 = fminf(m10 ? a10 : INFINITY, m11 ? a11 : INFINITY);
    #pragma unroll
    for (int off = 32; off; off >>= 1) {
        v0 = fminf(v0, __shfl_xor(v0, off, 64));
        v1 = fminf(v1, __shfl_xor(v1, off, 64));
    }
    if ((tid & 63) == 0) { s_red[0][tid >> 6] = v0; s_red[1][tid >> 6] = v1; }
    __syncthreads();
    const float amin0 = fminf(fminf(s_red[0][0], s_red[0][1]), fminf(s_red[0][2], s_red[0][3]));
    const float amin1 = fminf(fminf(s_red[1][0], s_red[1][1]), fminf(s_red[1][2], s_red[1][3]));
    __syncthreads();

    float p00 = m00 ? EXP2(LOG2E2 * (amin0 - a00)) : 0.f;
    float p01 = m01 ? EXP2(LOG2E2 * (amin0 - a01)) : 0.f;
    float p10 = m10 ? EXP2(LOG2E2 * (amin1 - a10)) : 0.f;
    float p11 = m11 ? EXP2(LOG2E2 * (amin1 - a11)) : 0.f;

    float s0 = p00 + p01, s1 = p10 + p11;
    #pragma unroll
    for (int off = 32; off; off >>= 1) {
        s0 += __shfl_xor(s0, off, 64);
        s1 += __shfl_xor(s1, off, 64);
    }
    if ((tid & 63) == 0) { s_red[0][tid >> 6] = s0; s_red[1][tid >> 6] = s1; }
    __syncthreads();
    const float inv0 = __fdividef(1.0f, (s_red[0][0] + s_red[0][1]) + (s_red[0][2] + s_red[0][3]));
    const float inv1 = __fdividef(1.0f, (s_red[1][0] + s_red[1][1]) + (s_red[1][2] + s_red[1][3]));

    p00 *= inv0; p01 *= inv0; p10 *= inv1; p11 *= inv1;

    attn_out[mb0 + tid] = p00;  attn_out[mb0 + tid + 256] = p01;
    attn_out[mb1 + tid] = p10;  attn_out[mb1 + tid + 256] = p11;
    s_p0[tid] = p00;  s_p0[tid + 256] = p01;
    s_p1[tid] = p10;  s_p1[tid + 256] = p11;
    __syncthreads();

    // ---- phase 3: out[i,d] = sum_j p[j] * h[b,j,d]; h load shared by both rows ----
    const float* __restrict__ hb = h + (size_t)b * SEQ * DM + tid;
    const float4* __restrict__ pv0 = (const float4*)s_p0;
    const float4* __restrict__ pv1 = (const float4*)s_p1;
    float acc0 = 0.f, acc1 = 0.f;
    #pragma unroll 2
    for (int j4 = 0; j4 < SEQ/4; j4++) {
        const float4 pA = pv0[j4];
        const float4 pB = pv1[j4];
        const float h0 = hb[(size_t)(4*j4 + 0) * DM];
        const float h1 = hb[(size_t)(4*j4 + 1) * DM];
        const float h2 = hb[(size_t)(4*j4 + 2) * DM];
        const float h3 = hb[(size_t)(4*j4 + 3) * DM];
        acc0 = fmaf(pA.x, h0, fmaf(pA.y, h1, fmaf(pA.z, h2, fmaf(pA.w, h3, acc0))));
        acc1 = fmaf(pB.x, h0, fmaf(pB.y, h1, fmaf(pB.z, h2, fmaf(pB.w, h3, acc1))));
    }
    out[(size_t)(b * SEQ + i0) * DM + tid]       = acc0;
    out[(size_t)(b * SEQ + i0 + 1) * DM + tid]   = acc1;
}

extern "C" void kernel_launch(void* const* d_in, const int* in_sizes, int n_in,
                              void* d_out, int out_size, void* d_ws, size_t ws_size,
                              hipStream_t stream) {
    const float* x    = (const float*)d_in[0];
    const float* pos  = (const float*)d_in[1];
    const int*   mask = (const int*)  d_in[2];
    const float* Wx   = (const float*)d_in[3];
    const float* bx   = (const float*)d_in[4];
    const float* Wp   = (const float*)d_in[5];
    const float* bp   = (const float*)d_in[6];
    const float* wv   = (const float*)d_in[7];

    float* out      = (float*)d_out;                          // [B,N,DM]
    float* attn_out = (float*)d_out + (size_t)BATCH*SEQ*DM;   // [B,N,N]

    char* ws  = (char*)d_ws;
    float* h   = (float*)(ws);                                // 1 MB
    float* EA  = (float*)(ws + (size_t)BATCH*SEQ*DM*4);       // 1 MB
    float* EB2 = (float*)(ws + 2*(size_t)BATCH*SEQ*DM*4);     // 1 MB

    pre_kernel<<<BATCH*SEQ, 256, 0, stream>>>(pos, Wp, bp, EA, EB2);
    h_kernel<<<(BATCH*SEQ)/4, 256, 0, stream>>>(x, Wx, bx, h);
    attn_kernel<<<(BATCH*SEQ)/2, 256, 0, stream>>>(mask, wv, EA, EB2, h, out, attn_out);
}

// Round 4
// 130.397 us; speedup vs baseline: 1.5150x; 1.0942x over previous
//
#include <hip/hip_runtime.h>
#include <hip/hip_bf16.h>
#include <math.h>

// Problem constants (from reference)
#define BATCH   2
#define SEQ     512     // N
#define DIN     512
#define DM      256     // d_model

#define LOG2E2  2.88539008177792681f   // 2*log2(e)

#if __has_builtin(__builtin_amdgcn_exp2f)
#define EXP2(x) __builtin_amdgcn_exp2f(x)
#else
#define EXP2(x) exp2f(x)
#endif
#if __has_builtin(__builtin_amdgcn_rcpf)
#define RCP(x) __builtin_amdgcn_rcpf(x)
#else
#define RCP(x) (1.0f / (x))
#endif

// tanh(t) with targ = 2*log2(e)*t: tanh = 1 - 2/(1 + exp2(targ)); overflow-safe.
__device__ __forceinline__ float tanh_from_scaled(float targ) {
    return fmaf(-2.0f, RCP(1.0f + EXP2(targ)), 1.0f);
}

// ---------------- Kernel 1: fused pre (EA/EB tables) + h = tanh(x@Wx+bx) ----------------
// grid = 1024 + 256 blocks, 256 threads.
//  blocks [0,1024):   pre — EA[b,i,d] = exp2(c*(pos_i.Wp_d + bp_d)); EB[b][d][j] = exp2(-c*pos_j.Wp_d)
//  blocks [1024,1280): h  — 4 rows per block, wave = row, lane = 4 cols.
__global__ __launch_bounds__(256) void prep_kernel(
    const float* __restrict__ pos,   // [B, N, 4]
    const float* __restrict__ Wp,    // [4, DM]
    const float* __restrict__ bp,    // [DM]
    const float* __restrict__ x,     // [B*N, DIN]
    const float* __restrict__ Wx,    // [DIN, DM]
    const float* __restrict__ bx,    // [DM]
    float* __restrict__ EA,          // [B*N, DM]
    float* __restrict__ EB,          // [B][DM][SEQ]
    float* __restrict__ h)           // [B*N, DM]
{
    __shared__ float4 s_x[4][DIN/4];   // 8 KB (used by h blocks only)

    const int tid = threadIdx.x;

    if (blockIdx.x < BATCH * SEQ) {
        // ---- pre part ----
        const int bi = blockIdx.x;
        const int b  = bi >> 9;
        const int n  = bi & (SEQ - 1);
        const int d  = tid;

        const float4 p = ((const float4*)pos)[bi];   // uniform -> s_load
        const float P = fmaf(p.x, Wp[d],
                        fmaf(p.y, Wp[DM + d],
                        fmaf(p.z, Wp[2*DM + d],
                             p.w * Wp[3*DM + d])));

        EA[(size_t)bi * DM + d] = EXP2(LOG2E2 * (P + bp[d]));        // coalesced
        EB[((size_t)(b * DM + d)) * SEQ + n] = EXP2(-LOG2E2 * P);    // scattered, L2-resident
        return;
    }

    // ---- h part ----
    const int w   = tid >> 6;          // wave id = local row
    const int l   = tid & 63;          // lane -> cols 4l..4l+3
    const int row = (blockIdx.x - BATCH * SEQ) * 4 + w;

    const float4* __restrict__ xr = (const float4*)(x + (size_t)row * DIN);
    s_x[w][l]      = xr[l];
    s_x[w][l + 64] = xr[l + 64];
    __syncthreads();

    float4 acc = ((const float4*)bx)[l];
    const float* __restrict__ wxp = Wx + 4 * l;

    #pragma unroll 2
    for (int k4 = 0; k4 < DIN/4; k4++) {
        const float4 xv = s_x[w][k4];                     // ds_read_b128 broadcast
        const float4 w0 = *(const float4*)(wxp + (size_t)(4*k4 + 0) * DM);
        const float4 w1 = *(const float4*)(wxp + (size_t)(4*k4 + 1) * DM);
        const float4 w2 = *(const float4*)(wxp + (size_t)(4*k4 + 2) * DM);
        const float4 w3 = *(const float4*)(wxp + (size_t)(4*k4 + 3) * DM);
        acc.x = fmaf(xv.x, w0.x, acc.x); acc.y = fmaf(xv.x, w0.y, acc.y);
        acc.z = fmaf(xv.x, w0.z, acc.z); acc.w = fmaf(xv.x, w0.w, acc.w);
        acc.x = fmaf(xv.y, w1.x, acc.x); acc.y = fmaf(xv.y, w1.y, acc.y);
        acc.z = fmaf(xv.y, w1.z, acc.z); acc.w = fmaf(xv.y, w1.w, acc.w);
        acc.x = fmaf(xv.z, w2.x, acc.x); acc.y = fmaf(xv.z, w2.y, acc.y);
        acc.z = fmaf(xv.z, w2.z, acc.z); acc.w = fmaf(xv.z, w2.w, acc.w);
        acc.x = fmaf(xv.w, w3.x, acc.x); acc.y = fmaf(xv.w, w3.y, acc.y);
        acc.z = fmaf(xv.w, w3.z, acc.z); acc.w = fmaf(xv.w, w3.w, acc.w);
    }

    float4 r;
    r.x = tanh_from_scaled(LOG2E2 * acc.x);
    r.y = tanh_from_scaled(LOG2E2 * acc.y);
    r.z = tanh_from_scaled(LOG2E2 * acc.z);
    r.w = tanh_from_scaled(LOG2E2 * acc.w);
    ((float4*)(h + (size_t)row * DM))[l] = r;
}

// ---------------- Kernel 2: scores + softmax + weighted sum ----------------
// grid = B*N/4 = 256 blocks (4 i-rows each), 512 threads (thread = j in phases 1/2).
__global__ __launch_bounds__(512) void attn_kernel(
    const int*   __restrict__ mask,  // [B, N, N]
    const float* __restrict__ wv,    // [DM]
    const float* __restrict__ EA,    // [B*N, DM]
    const float* __restrict__ EB,    // [B][DM][SEQ]
    const float* __restrict__ h,     // [B, N, DM]
    float* __restrict__ out,         // [B, N, DM]
    float* __restrict__ attn_out)    // [B, N, N]
{
    const int b   = blockIdx.x >> 7;      // 128 blocks per batch
    const int i0  = (blockIdx.x & 127) * 4;
    const int j   = threadIdx.x;          // 0..511

    __shared__ float s_p[4][SEQ];         // 8 KB
    __shared__ float s_red[4][8];

    const float* __restrict__ EAp = EA + (size_t)(b * SEQ + i0) * DM;   // uniform -> s_load
    const float* __restrict__ EBp = EB + (size_t)b * DM * SEQ + j;

    // ---- phase 1: a_r[j] = sum_d w_d / (1 + EA[i_r,d]*EB[d,j]) ----
    // score = const - 2a (softmax shift-invariant).
    float a0 = 0.f, a1 = 0.f, a2 = 0.f, a3 = 0.f;
    #pragma unroll 8
    for (int d = 0; d < DM; d++) {
        const float eb  = EBp[(size_t)d * SEQ];   // coalesced dword
        const float wd  = wv[d];
        const float ea0 = EAp[d];
        const float ea1 = EAp[DM + d];
        const float ea2 = EAp[2*DM + d];
        const float ea3 = EAp[3*DM + d];
        a0 = fmaf(wd, RCP(fmaf(ea0, eb, 1.0f)), a0);
        a1 = fmaf(wd, RCP(fmaf(ea1, eb, 1.0f)), a1);
        a2 = fmaf(wd, RCP(fmaf(ea2, eb, 1.0f)), a2);
        a3 = fmaf(wd, RCP(fmaf(ea3, eb, 1.0f)), a3);
    }

    // ---- phase 2: masked softmax, no max-shift (exponents are O(+-10), fp32-safe) ----
    const size_t mb = (size_t)b * SEQ * SEQ + (size_t)i0 * SEQ + j;
    const int m0 = mask[mb];
    const int m1 = mask[mb + SEQ];
    const int m2 = mask[mb + 2*SEQ];
    const int m3 = mask[mb + 3*SEQ];

    float p0 = m0 ? EXP2(-LOG2E2 * a0) : 0.f;
    float p1 = m1 ? EXP2(-LOG2E2 * a1) : 0.f;
    float p2 = m2 ? EXP2(-LOG2E2 * a2) : 0.f;
    float p3 = m3 ? EXP2(-LOG2E2 * a3) : 0.f;

    float s0 = p0, s1 = p1, s2 = p2, s3 = p3;
    #pragma unroll
    for (int off = 32; off; off >>= 1) {
        s0 += __shfl_xor(s0, off, 64);
        s1 += __shfl_xor(s1, off, 64);
        s2 += __shfl_xor(s2, off, 64);
        s3 += __shfl_xor(s3, off, 64);
    }
    const int w = j >> 6;                  // 8 waves
    if ((j & 63) == 0) {
        s_red[0][w] = s0; s_red[1][w] = s1; s_red[2][w] = s2; s_red[3][w] = s3;
    }
    __syncthreads();

    const float4 r0a = ((const float4*)s_red[0])[0], r0b = ((const float4*)s_red[0])[1];
    const float4 r1a = ((const float4*)s_red[1])[0], r1b = ((const float4*)s_red[1])[1];
    const float4 r2a = ((const float4*)s_red[2])[0], r2b = ((const float4*)s_red[2])[1];
    const float4 r3a = ((const float4*)s_red[3])[0], r3b = ((const float4*)s_red[3])[1];
    const float inv0 = __fdividef(1.0f, (r0a.x+r0a.y+r0a.z+r0a.w) + (r0b.x+r0b.y+r0b.z+r0b.w));
    const float inv1 = __fdividef(1.0f, (r1a.x+r1a.y+r1a.z+r1a.w) + (r1b.x+r1b.y+r1b.z+r1b.w));
    const float inv2 = __fdividef(1.0f, (r2a.x+r2a.y+r2a.z+r2a.w) + (r2b.x+r2b.y+r2b.z+r2b.w));
    const float inv3 = __fdividef(1.0f, (r3a.x+r3a.y+r3a.z+r3a.w) + (r3b.x+r3b.y+r3b.z+r3b.w));

    p0 *= inv0; p1 *= inv1; p2 *= inv2; p3 *= inv3;

    attn_out[mb]         = p0;
    attn_out[mb + SEQ]   = p1;
    attn_out[mb + 2*SEQ] = p2;
    attn_out[mb + 3*SEQ] = p3;
    s_p[0][j] = p0; s_p[1][j] = p1; s_p[2][j] = p2; s_p[3][j] = p3;
    __syncthreads();

    // ---- phase 3: out[i_r,d] = sum_j p_r[j] * h[b,j,d] ----
    // thread (rh = j>>8, d = j&255) handles rows i0+rh and i0+rh+2 (shared h loads).
    const int rh = j >> 8;
    const int d  = j & 255;
    const float* __restrict__ hb  = h + (size_t)b * SEQ * DM + d;
    const float4* __restrict__ pA = (const float4*)s_p[rh];
    const float4* __restrict__ pB = (const float4*)s_p[rh + 2];

    float accA = 0.f, accB = 0.f;
    #pragma unroll 4
    for (int j4 = 0; j4 < SEQ/4; j4++) {
        const float4 qA = pA[j4];
        const float4 qB = pB[j4];
        const float h0 = hb[(size_t)(4*j4 + 0) * DM];
        const float h1 = hb[(size_t)(4*j4 + 1) * DM];
        const float h2 = hb[(size_t)(4*j4 + 2) * DM];
        const float h3 = hb[(size_t)(4*j4 + 3) * DM];
        accA = fmaf(qA.x, h0, fmaf(qA.y, h1, fmaf(qA.z, h2, fmaf(qA.w, h3, accA))));
        accB = fmaf(qB.x, h0, fmaf(qB.y, h1, fmaf(qB.z, h2, fmaf(qB.w, h3, accB))));
    }
    out[(size_t)(b * SEQ + i0 + rh) * DM + d]     = accA;
    out[(size_t)(b * SEQ + i0 + rh + 2) * DM + d] = accB;
}

extern "C" void kernel_launch(void* const* d_in, const int* in_sizes, int n_in,
                              void* d_out, int out_size, void* d_ws, size_t ws_size,
                              hipStream_t stream) {
    const float* x    = (const float*)d_in[0];
    const float* pos  = (const float*)d_in[1];
    const int*   mask = (const int*)  d_in[2];
    const float* Wx   = (const float*)d_in[3];
    const float* bx   = (const float*)d_in[4];
    const float* Wp   = (const float*)d_in[5];
    const float* bp   = (const float*)d_in[6];
    const float* wv   = (const float*)d_in[7];

    float* out      = (float*)d_out;                          // [B,N,DM]
    float* attn_out = (float*)d_out + (size_t)BATCH*SEQ*DM;   // [B,N,N]

    char* ws  = (char*)d_ws;
    float* h  = (float*)(ws);                                 // 1 MB
    float* EA = (float*)(ws + (size_t)BATCH*SEQ*DM*4);        // 1 MB
    float* EB = (float*)(ws + 2*(size_t)BATCH*SEQ*DM*4);      // 1 MB

    prep_kernel<<<BATCH*SEQ + (BATCH*SEQ)/4, 256, 0, stream>>>(pos, Wp, bp, x, Wx, bx, EA, EB, h);
    attn_kernel<<<(BATCH*SEQ)/4, 512, 0, stream>>>(mask, wv, EA, EB, h, out, attn_out);
}

// Round 5
// 128.276 us; speedup vs baseline: 1.5400x; 1.0165x over previous
//
#include <hip/hip_runtime.h>
#include <hip/hip_bf16.h>
#include <math.h>

// Problem constants (from reference)
#define BATCH   2
#define SEQ     512     // N
#define DIN     512
#define DM      256     // d_model

#define LOG2E2  2.88539008177792681f   // 2*log2(e)

#if __has_builtin(__builtin_amdgcn_exp2f)
#define EXP2(x) __builtin_amdgcn_exp2f(x)
#else
#define EXP2(x) exp2f(x)
#endif
#if __has_builtin(__builtin_amdgcn_rcpf)
#define RCP(x) __builtin_amdgcn_rcpf(x)
#else
#define RCP(x) (1.0f / (x))
#endif

// tanh(t) with targ = 2*log2(e)*t: tanh = 1 - 2/(1 + exp2(targ)); overflow-safe.
__device__ __forceinline__ float tanh_from_scaled(float targ) {
    return fmaf(-2.0f, RCP(1.0f + EXP2(targ)), 1.0f);
}

#define PRE_BLOCKS (BATCH * DM)          // 512
#define H_BLOCKS   ((BATCH * SEQ) / 4)   // 256, 4 rows/block, k split across wave pairs

// ---------------- Kernel 1: fused pre (EA/EB tables, transposed) + h = tanh(x@Wx+bx) ----
// 512 threads/block.
//  blocks [0, 512):    pre — block=(b,d), thread=n. All loads/stores coalesced.
//    EAt[b][d][i] = exp2(c*(pos_i.Wp_d + bp_d));  EB[b][d][j] = exp2(-c*pos_j.Wp_d)
//  blocks [512, 768):  h — 4 rows/block; row r handled by waves (r, r+4) splitting k.
__global__ __launch_bounds__(512) void prep_kernel(
    const float* __restrict__ pos,   // [B, N, 4]
    const float* __restrict__ Wp,    // [4, DM]
    const float* __restrict__ bp,    // [DM]
    const float* __restrict__ x,     // [B*N, DIN]
    const float* __restrict__ Wx,    // [DIN, DM]
    const float* __restrict__ bx,    // [DM]
    float* __restrict__ EAt,         // [B][DM][SEQ]
    float* __restrict__ EB,          // [B][DM][SEQ]
    float* __restrict__ h)           // [B*N, DM]
{
    const int tid = threadIdx.x;

    if (blockIdx.x < PRE_BLOCKS) {
        // ---- pre part: block = (b, d), thread = n ----
        const int b = blockIdx.x >> 8;
        const int d = blockIdx.x & 255;
        const int n = tid;

        const float wp0 = Wp[d];            // uniform -> s_load
        const float wp1 = Wp[DM + d];
        const float wp2 = Wp[2*DM + d];
        const float wp3 = Wp[3*DM + d];
        const float bpd = bp[d];

        const float4 p = ((const float4*)pos)[b * SEQ + n];   // coalesced 16B
        const float P = fmaf(p.x, wp0, fmaf(p.y, wp1, fmaf(p.z, wp2, p.w * wp3)));

        const size_t o = ((size_t)(b * DM + d)) * SEQ + n;
        EAt[o] = EXP2(LOG2E2 * (P + bpd));    // coalesced dword store
        EB[o]  = EXP2(-LOG2E2 * P);           // coalesced dword store
        return;
    }

    // ---- h part: 4 rows/block, wave w = (r = w&3, half = w>>2) ----
    __shared__ float4 s_x[4][DIN/4];     // 8 KB
    __shared__ float4 s_part[4][64];     // 4 KB

    const int w    = tid >> 6;
    const int l    = tid & 63;
    const int r    = w & 3;
    const int half = w >> 2;
    const int row  = (blockIdx.x - PRE_BLOCKS) * 4 + r;

    // each wave stages the k-half of x it will consume (same-wave LDS write->read)
    const float4* __restrict__ xr = (const float4*)(x + (size_t)row * DIN);
    s_x[r][half * 64 + l] = xr[half * 64 + l];
    __syncthreads();

    float4 acc = half ? make_float4(0.f, 0.f, 0.f, 0.f) : ((const float4*)bx)[l];
    const float* __restrict__ wxp = Wx + 4 * l;

    #pragma unroll 2
    for (int k4 = 0; k4 < 64; k4++) {
        const int kk = half * 64 + k4;
        const float4 xv = s_x[r][kk];                     // ds_read_b128 broadcast
        const float4 w0 = *(const float4*)(wxp + (size_t)(4*kk + 0) * DM);
        const float4 w1 = *(const float4*)(wxp + (size_t)(4*kk + 1) * DM);
        const float4 w2 = *(const float4*)(wxp + (size_t)(4*kk + 2) * DM);
        const float4 w3 = *(const float4*)(wxp + (size_t)(4*kk + 3) * DM);
        acc.x = fmaf(xv.x, w0.x, acc.x); acc.y = fmaf(xv.x, w0.y, acc.y);
        acc.z = fmaf(xv.x, w0.z, acc.z); acc.w = fmaf(xv.x, w0.w, acc.w);
        acc.x = fmaf(xv.y, w1.x, acc.x); acc.y = fmaf(xv.y, w1.y, acc.y);
        acc.z = fmaf(xv.y, w1.z, acc.z); acc.w = fmaf(xv.y, w1.w, acc.w);
        acc.x = fmaf(xv.z, w2.x, acc.x); acc.y = fmaf(xv.z, w2.y, acc.y);
        acc.z = fmaf(xv.z, w2.z, acc.z); acc.w = fmaf(xv.z, w2.w, acc.w);
        acc.x = fmaf(xv.w, w3.x, acc.x); acc.y = fmaf(xv.w, w3.y, acc.y);
        acc.z = fmaf(xv.w, w3.z, acc.z); acc.w = fmaf(xv.w, w3.w, acc.w);
    }

    if (half) s_part[r][l] = acc;        // upper k-half publishes its partial
    __syncthreads();
    if (!half) {
        const float4 q = s_part[r][l];
        float4 t;
        t.x = tanh_from_scaled(LOG2E2 * (acc.x + q.x));
        t.y = tanh_from_scaled(LOG2E2 * (acc.y + q.y));
        t.z = tanh_from_scaled(LOG2E2 * (acc.z + q.z));
        t.w = tanh_from_scaled(LOG2E2 * (acc.w + q.w));
        ((float4*)(h + (size_t)row * DM))[l] = t;
    }
}

// ---------------- Kernel 2: scores + softmax + weighted sum ----------------
// grid = B*N/4 = 256 blocks (4 i-rows each), 512 threads (thread = j in phases 1/2).
__global__ __launch_bounds__(512) void attn_kernel(
    const int*   __restrict__ mask,  // [B, N, N]
    const float* __restrict__ wv,    // [DM]
    const float* __restrict__ EAt,   // [B][DM][SEQ]
    const float* __restrict__ EB,    // [B][DM][SEQ]
    const float* __restrict__ h,     // [B, N, DM]
    float* __restrict__ out,         // [B, N, DM]
    float* __restrict__ attn_out)    // [B, N, N]
{
    const int b   = blockIdx.x >> 7;      // 128 blocks per batch
    const int i0  = (blockIdx.x & 127) * 4;
    const int j   = threadIdx.x;          // 0..511

    __shared__ float s_p[4][SEQ];         // 8 KB
    __shared__ float s_red[4][8];

    const float* __restrict__ EAb = EAt + (size_t)b * DM * SEQ + i0;   // uniform
    const float* __restrict__ EBp = EB  + (size_t)b * DM * SEQ + j;

    // ---- phase 1: a_r[j] = sum_d w_d / (1 + EA[d,i_r]*EB[d,j]) ----
    // score = const - 2a (softmax shift-invariant).
    float a0 = 0.f, a1 = 0.f, a2 = 0.f, a3 = 0.f;
    #pragma unroll 8
    for (int d = 0; d < DM; d++) {
        const float  eb = EBp[(size_t)d * SEQ];                         // coalesced dword
        const float4 ea = *(const float4*)(EAb + (size_t)d * SEQ);      // s_load_dwordx4
        const float  wd = wv[d];
        a0 = fmaf(wd, RCP(fmaf(ea.x, eb, 1.0f)), a0);
        a1 = fmaf(wd, RCP(fmaf(ea.y, eb, 1.0f)), a1);
        a2 = fmaf(wd, RCP(fmaf(ea.z, eb, 1.0f)), a2);
        a3 = fmaf(wd, RCP(fmaf(ea.w, eb, 1.0f)), a3);
    }

    // ---- phase 2: masked softmax, no max-shift (exponents O(1), fp32-safe) ----
    const size_t mb = (size_t)b * SEQ * SEQ + (size_t)i0 * SEQ + j;
    const int m0 = mask[mb];
    const int m1 = mask[mb + SEQ];
    const int m2 = mask[mb + 2*SEQ];
    const int m3 = mask[mb + 3*SEQ];

    float p0 = m0 ? EXP2(-LOG2E2 * a0) : 0.f;
    float p1 = m1 ? EXP2(-LOG2E2 * a1) : 0.f;
    float p2 = m2 ? EXP2(-LOG2E2 * a2) : 0.f;
    float p3 = m3 ? EXP2(-LOG2E2 * a3) : 0.f;

    float s0 = p0, s1 = p1, s2 = p2, s3 = p3;
    #pragma unroll
    for (int off = 32; off; off >>= 1) {
        s0 += __shfl_xor(s0, off, 64);
        s1 += __shfl_xor(s1, off, 64);
        s2 += __shfl_xor(s2, off, 64);
        s3 += __shfl_xor(s3, off, 64);
    }
    const int w = j >> 6;                  // 8 waves
    if ((j & 63) == 0) {
        s_red[0][w] = s0; s_red[1][w] = s1; s_red[2][w] = s2; s_red[3][w] = s3;
    }
    __syncthreads();

    const float4 r0a = ((const float4*)s_red[0])[0], r0b = ((const float4*)s_red[0])[1];
    const float4 r1a = ((const float4*)s_red[1])[0], r1b = ((const float4*)s_red[1])[1];
    const float4 r2a = ((const float4*)s_red[2])[0], r2b = ((const float4*)s_red[2])[1];
    const float4 r3a = ((const float4*)s_red[3])[0], r3b = ((const float4*)s_red[3])[1];
    const float inv0 = __fdividef(1.0f, (r0a.x+r0a.y+r0a.z+r0a.w) + (r0b.x+r0b.y+r0b.z+r0b.w));
    const float inv1 = __fdividef(1.0f, (r1a.x+r1a.y+r1a.z+r1a.w) + (r1b.x+r1b.y+r1b.z+r1b.w));
    const float inv2 = __fdividef(1.0f, (r2a.x+r2a.y+r2a.z+r2a.w) + (r2b.x+r2b.y+r2b.z+r2b.w));
    const float inv3 = __fdividef(1.0f, (r3a.x+r3a.y+r3a.z+r3a.w) + (r3b.x+r3b.y+r3b.z+r3b.w));

    p0 *= inv0; p1 *= inv1; p2 *= inv2; p3 *= inv3;

    attn_out[mb]         = p0;
    attn_out[mb + SEQ]   = p1;
    attn_out[mb + 2*SEQ] = p2;
    attn_out[mb + 3*SEQ] = p3;
    s_p[0][j] = p0; s_p[1][j] = p1; s_p[2][j] = p2; s_p[3][j] = p3;
    __syncthreads();

    // ---- phase 3: out[i_r,d] = sum_j p_r[j] * h[b,j,d] ----
    // thread (rh = j>>8, d = j&255) handles rows i0+rh and i0+rh+2 (shared h loads).
    const int rh = j >> 8;
    const int d  = j & 255;
    const float* __restrict__ hb  = h + (size_t)b * SEQ * DM + d;
    const float4* __restrict__ pA = (const float4*)s_p[rh];
    const float4* __restrict__ pB = (const float4*)s_p[rh + 2];

    float accA = 0.f, accB = 0.f;
    #pragma unroll 4
    for (int j4 = 0; j4 < SEQ/4; j4++) {
        const float4 qA = pA[j4];
        const float4 qB = pB[j4];
        const float h0 = hb[(size_t)(4*j4 + 0) * DM];
        const float h1 = hb[(size_t)(4*j4 + 1) * DM];
        const float h2 = hb[(size_t)(4*j4 + 2) * DM];
        const float h3 = hb[(size_t)(4*j4 + 3) * DM];
        accA = fmaf(qA.x, h0, fmaf(qA.y, h1, fmaf(qA.z, h2, fmaf(qA.w, h3, accA))));
        accB = fmaf(qB.x, h0, fmaf(qB.y, h1, fmaf(qB.z, h2, fmaf(qB.w, h3, accB))));
    }
    out[(size_t)(b * SEQ + i0 + rh) * DM + d]     = accA;
    out[(size_t)(b * SEQ + i0 + rh + 2) * DM + d] = accB;
}

extern "C" void kernel_launch(void* const* d_in, const int* in_sizes, int n_in,
                              void* d_out, int out_size, void* d_ws, size_t ws_size,
                              hipStream_t stream) {
    const float* x    = (const float*)d_in[0];
    const float* pos  = (const float*)d_in[1];
    const int*   mask = (const int*)  d_in[2];
    const float* Wx   = (const float*)d_in[3];
    const float* bx   = (const float*)d_in[4];
    const float* Wp   = (const float*)d_in[5];
    const float* bp   = (const float*)d_in[6];
    const float* wv   = (const float*)d_in[7];

    float* out      = (float*)d_out;                          // [B,N,DM]
    float* attn_out = (float*)d_out + (size_t)BATCH*SEQ*DM;   // [B,N,N]

    char* ws   = (char*)d_ws;
    float* h   = (float*)(ws);                                // 1 MB
    float* EAt = (float*)(ws + (size_t)BATCH*SEQ*DM*4);       // 1 MB
    float* EB  = (float*)(ws + 2*(size_t)BATCH*SEQ*DM*4);     // 1 MB

    prep_kernel<<<PRE_BLOCKS + H_BLOCKS, 512, 0, stream>>>(pos, Wp, bp, x, Wx, bx, EAt, EB, h);
    attn_kernel<<<(BATCH*SEQ)/4, 512, 0, stream>>>(mask, wv, EAt, EB, h, out, attn_out);
}

// Round 6
// 124.118 us; speedup vs baseline: 1.5916x; 1.0335x over previous
//
#include <hip/hip_runtime.h>
#include <hip/hip_bf16.h>
#include <math.h>

// Problem constants (from reference)
#define BATCH   2
#define SEQ     512     // N
#define DIN     512
#define DM      256     // d_model

#define LOG2E2  2.88539008177792681f   // 2*log2(e)

#if __has_builtin(__builtin_amdgcn_exp2f)
#define EXP2(x) __builtin_amdgcn_exp2f(x)
#else
#define EXP2(x) exp2f(x)
#endif
#if __has_builtin(__builtin_amdgcn_rcpf)
#define RCP(x) __builtin_amdgcn_rcpf(x)
#else
#define RCP(x) (1.0f / (x))
#endif

// tanh(t) with targ = 2*log2(e)*t: tanh = 1 - 2/(1 + exp2(targ)); overflow-safe.
__device__ __forceinline__ float tanh_from_scaled(float targ) {
    return fmaf(-2.0f, RCP(1.0f + EXP2(targ)), 1.0f);
}

#define PRE_BLOCKS (BATCH * DM)          // 512
#define H_BLOCKS   ((BATCH * SEQ) / 4)   // 256, 4 rows/block, k split across wave pairs

// ---------------- Kernel 1: fused pre (EA/EB tables, transposed) + h = tanh(x@Wx+bx) ----
// 512 threads/block.
//  blocks [0, 512):    pre — block=(b,d), thread=n. All loads/stores coalesced.
//    EAt[b][d][i] = exp2(c*(pos_i.Wp_d + bp_d));  EB[b][d][j] = exp2(-c*pos_j.Wp_d)
//  blocks [512, 768):  h — 4 rows/block; row r handled by waves (r, r+4) splitting k.
__global__ __launch_bounds__(512) void prep_kernel(
    const float* __restrict__ pos,   // [B, N, 4]
    const float* __restrict__ Wp,    // [4, DM]
    const float* __restrict__ bp,    // [DM]
    const float* __restrict__ x,     // [B*N, DIN]
    const float* __restrict__ Wx,    // [DIN, DM]
    const float* __restrict__ bx,    // [DM]
    float* __restrict__ EAt,         // [B][DM][SEQ]
    float* __restrict__ EB,          // [B][DM][SEQ]
    float* __restrict__ h)           // [B*N, DM]
{
    const int tid = threadIdx.x;

    if (blockIdx.x < PRE_BLOCKS) {
        // ---- pre part: block = (b, d), thread = n ----
        const int b = blockIdx.x >> 8;
        const int d = blockIdx.x & 255;
        const int n = tid;

        const float wp0 = Wp[d];            // uniform -> s_load
        const float wp1 = Wp[DM + d];
        const float wp2 = Wp[2*DM + d];
        const float wp3 = Wp[3*DM + d];
        const float bpd = bp[d];

        const float4 p = ((const float4*)pos)[b * SEQ + n];   // coalesced 16B
        const float P = fmaf(p.x, wp0, fmaf(p.y, wp1, fmaf(p.z, wp2, p.w * wp3)));

        const size_t o = ((size_t)(b * DM + d)) * SEQ + n;
        EAt[o] = EXP2(LOG2E2 * (P + bpd));    // coalesced dword store
        EB[o]  = EXP2(-LOG2E2 * P);           // coalesced dword store
        return;
    }

    // ---- h part: 4 rows/block, wave w = (r = w&3, half = w>>2) ----
    __shared__ float4 s_x[4][DIN/4];     // 8 KB
    __shared__ float4 s_part[4][64];     // 4 KB

    const int w    = tid >> 6;
    const int l    = tid & 63;
    const int r    = w & 3;
    const int half = w >> 2;
    const int row  = (blockIdx.x - PRE_BLOCKS) * 4 + r;

    // each wave stages the k-half of x it will consume (same-wave LDS write->read)
    const float4* __restrict__ xr = (const float4*)(x + (size_t)row * DIN);
    s_x[r][half * 64 + l] = xr[half * 64 + l];
    __syncthreads();

    float4 acc = half ? make_float4(0.f, 0.f, 0.f, 0.f) : ((const float4*)bx)[l];
    const float* __restrict__ wxp = Wx + 4 * l;

    #pragma unroll 2
    for (int k4 = 0; k4 < 64; k4++) {
        const int kk = half * 64 + k4;
        const float4 xv = s_x[r][kk];                     // ds_read_b128 broadcast
        const float4 w0 = *(const float4*)(wxp + (size_t)(4*kk + 0) * DM);
        const float4 w1 = *(const float4*)(wxp + (size_t)(4*kk + 1) * DM);
        const float4 w2 = *(const float4*)(wxp + (size_t)(4*kk + 2) * DM);
        const float4 w3 = *(const float4*)(wxp + (size_t)(4*kk + 3) * DM);
        acc.x = fmaf(xv.x, w0.x, acc.x); acc.y = fmaf(xv.x, w0.y, acc.y);
        acc.z = fmaf(xv.x, w0.z, acc.z); acc.w = fmaf(xv.x, w0.w, acc.w);
        acc.x = fmaf(xv.y, w1.x, acc.x); acc.y = fmaf(xv.y, w1.y, acc.y);
        acc.z = fmaf(xv.y, w1.z, acc.z); acc.w = fmaf(xv.y, w1.w, acc.w);
        acc.x = fmaf(xv.z, w2.x, acc.x); acc.y = fmaf(xv.z, w2.y, acc.y);
        acc.z = fmaf(xv.z, w2.z, acc.z); acc.w = fmaf(xv.z, w2.w, acc.w);
        acc.x = fmaf(xv.w, w3.x, acc.x); acc.y = fmaf(xv.w, w3.y, acc.y);
        acc.z = fmaf(xv.w, w3.z, acc.z); acc.w = fmaf(xv.w, w3.w, acc.w);
    }

    if (half) s_part[r][l] = acc;        // upper k-half publishes its partial
    __syncthreads();
    if (!half) {
        const float4 q = s_part[r][l];
        float4 t;
        t.x = tanh_from_scaled(LOG2E2 * (acc.x + q.x));
        t.y = tanh_from_scaled(LOG2E2 * (acc.y + q.y));
        t.z = tanh_from_scaled(LOG2E2 * (acc.z + q.z));
        t.w = tanh_from_scaled(LOG2E2 * (acc.w + q.w));
        ((float4*)(h + (size_t)row * DM))[l] = t;
    }
}

// ---------------- Kernel 2: scores + softmax + weighted sum ----------------
// grid = B*N/4 = 256 blocks (4 i-rows each), 1024 threads (16 waves).
// Phase 1/2: thread = (j = tid&511, rg = tid>>9); rg-half owns rows {2rg, 2rg+1}.
__global__ __launch_bounds__(1024) void attn_kernel(
    const int*   __restrict__ mask,  // [B, N, N]
    const float* __restrict__ wv,    // [DM]
    const float* __restrict__ EAt,   // [B][DM][SEQ]
    const float* __restrict__ EB,    // [B][DM][SEQ]
    const float* __restrict__ h,     // [B, N, DM]
    float* __restrict__ out,         // [B, N, DM]
    float* __restrict__ attn_out)    // [B, N, N]
{
    const int b   = blockIdx.x >> 7;      // 128 blocks per batch
    const int i0  = (blockIdx.x & 127) * 4;
    const int tid = threadIdx.x;          // 0..1023
    const int j   = tid & 511;
    const int rg  = tid >> 9;             // 0/1 -> rows {2rg, 2rg+1}

    __shared__ float4 s_ead[DM][2];       // {EA[d][i0+2g], EA[d][i0+2g+1], w[d], 0} : 8 KB
    __shared__ float  s_p[4][SEQ];        // 8 KB
    __shared__ float  s_red[4][8];

    // ---- stage EA rows + w into LDS (one-time) ----
    if (tid < 2 * DM) {
        const int d = tid >> 1;
        const int g = tid & 1;
        const float2 ea = *(const float2*)(EAt + ((size_t)b * DM + d) * SEQ + i0 + 2 * g);
        s_ead[d][g] = make_float4(ea.x, ea.y, wv[d], 0.f);
    }
    __syncthreads();

    const float* __restrict__ EBp = EB + (size_t)b * DM * SEQ + j;
    const float4* __restrict__ eap = &s_ead[0][rg];   // rg folded into base

    // ---- phase 1: a_r[j] = sum_d w_d / (1 + EA[d,r]*EB[d,j]) ----
    // score = const - 2a (softmax shift-invariant).
    float a0 = 0.f, a1 = 0.f;
    #pragma unroll 8
    for (int d = 0; d < DM; d++) {
        const float  eb = EBp[(size_t)d * SEQ];   // coalesced dword (L2)
        const float4 ea = eap[2 * d];             // ds_read_b128 broadcast
        a0 = fmaf(ea.z, RCP(fmaf(ea.x, eb, 1.0f)), a0);
        a1 = fmaf(ea.z, RCP(fmaf(ea.y, eb, 1.0f)), a1);
    }

    // ---- phase 2: masked softmax, no max-shift (exponents O(10), fp32-safe) ----
    const int r0 = 2 * rg, r1 = 2 * rg + 1;
    const size_t mb = (size_t)b * SEQ * SEQ + (size_t)i0 * SEQ + j;
    const int m0 = mask[mb + (size_t)r0 * SEQ];
    const int m1 = mask[mb + (size_t)r1 * SEQ];

    float p0 = m0 ? EXP2(-LOG2E2 * a0) : 0.f;
    float p1 = m1 ? EXP2(-LOG2E2 * a1) : 0.f;

    float s0 = p0, s1 = p1;
    #pragma unroll
    for (int off = 32; off; off >>= 1) {
        s0 += __shfl_xor(s0, off, 64);
        s1 += __shfl_xor(s1, off, 64);
    }
    const int w = tid >> 6;                // 0..15
    if ((tid & 63) == 0) {
        s_red[r0][w & 7] = s0;
        s_red[r1][w & 7] = s1;
    }
    __syncthreads();

    const float4 ra = ((const float4*)s_red[r0])[0], rb = ((const float4*)s_red[r0])[1];
    const float4 rc = ((const float4*)s_red[r1])[0], rd = ((const float4*)s_red[r1])[1];
    const float inv0 = __fdividef(1.0f, (ra.x+ra.y+ra.z+ra.w) + (rb.x+rb.y+rb.z+rb.w));
    const float inv1 = __fdividef(1.0f, (rc.x+rc.y+rc.z+rc.w) + (rd.x+rd.y+rd.z+rd.w));

    p0 *= inv0;
    p1 *= inv1;

    attn_out[mb + (size_t)r0 * SEQ] = p0;
    attn_out[mb + (size_t)r1 * SEQ] = p1;
    s_p[r0][j] = p0;
    s_p[r1][j] = p1;
    __syncthreads();

    // ---- phase 3: out[i_r,d] = sum_j p_r[j] * h[b,j,d] ----
    // threads [0,512): (rh = tid>>8, d = tid&255) -> rows i0+rh, i0+rh+2 (shared h loads).
    if (tid < 512) {
        const int rh = tid >> 8;
        const int d  = tid & 255;
        const float* __restrict__ hb  = h + (size_t)b * SEQ * DM + d;
        const float4* __restrict__ pA = (const float4*)s_p[rh];
        const float4* __restrict__ pB = (const float4*)s_p[rh + 2];

        float accA = 0.f, accB = 0.f;
        #pragma unroll 4
        for (int j4 = 0; j4 < SEQ/4; j4++) {
            const float4 qA = pA[j4];
            const float4 qB = pB[j4];
            const float h0 = hb[(size_t)(4*j4 + 0) * DM];
            const float h1 = hb[(size_t)(4*j4 + 1) * DM];
            const float h2 = hb[(size_t)(4*j4 + 2) * DM];
            const float h3 = hb[(size_t)(4*j4 + 3) * DM];
            accA = fmaf(qA.x, h0, fmaf(qA.y, h1, fmaf(qA.z, h2, fmaf(qA.w, h3, accA))));
            accB = fmaf(qB.x, h0, fmaf(qB.y, h1, fmaf(qB.z, h2, fmaf(qB.w, h3, accB))));
        }
        out[(size_t)(b * SEQ + i0 + rh) * DM + d]     = accA;
        out[(size_t)(b * SEQ + i0 + rh + 2) * DM + d] = accB;
    }
}

extern "C" void kernel_launch(void* const* d_in, const int* in_sizes, int n_in,
                              void* d_out, int out_size, void* d_ws, size_t ws_size,
                              hipStream_t stream) {
    const float* x    = (const float*)d_in[0];
    const float* pos  = (const float*)d_in[1];
    const int*   mask = (const int*)  d_in[2];
    const float* Wx   = (const float*)d_in[3];
    const float* bx   = (const float*)d_in[4];
    const float* Wp   = (const float*)d_in[5];
    const float* bp   = (const float*)d_in[6];
    const float* wv   = (const float*)d_in[7];

    float* out      = (float*)d_out;                          // [B,N,DM]
    float* attn_out = (float*)d_out + (size_t)BATCH*SEQ*DM;   // [B,N,N]

    char* ws   = (char*)d_ws;
    float* h   = (float*)(ws);                                // 1 MB
    float* EAt = (float*)(ws + (size_t)BATCH*SEQ*DM*4);       // 1 MB
    float* EB  = (float*)(ws + 2*(size_t)BATCH*SEQ*DM*4);     // 1 MB

    prep_kernel<<<PRE_BLOCKS + H_BLOCKS, 512, 0, stream>>>(pos, Wp, bp, x, Wx, bx, EAt, EB, h);
    attn_kernel<<<(BATCH*SEQ)/4, 1024, 0, stream>>>(mask, wv, EAt, EB, h, out, attn_out);
}